// Round 1
// baseline (3180.766 us; speedup 1.0000x reference)
//
#include <hip/hip_runtime.h>
#include <cmath>

#define EMB_V 100000
#define EMB_E 256
#define HID   256
#define G3    768
#define BATCH 256
#define SUBS  10
#define BC    2560
#define TC    20
#define TS    50

__device__ __forceinline__ float sigmoidf_(float x) { return 1.f / (1.f + expf(-x)); }

// out is [cols][rows]: out[c*rows + r] = in[r*cols + c]
__global__ void transpose_rm(const float* __restrict__ in, float* __restrict__ out,
                             int rows, int cols) {
    int o = blockIdx.x * 256 + threadIdx.x;
    if (o >= rows * cols) return;
    int c = o / rows;
    int r = o - c * rows;
    out[o] = in[r * cols + c];
}

// Fused GRU scan: per block, R rows, T steps. Computes both input-gate GEMM
// (x = emb[idx]) and recurrent GEMM per step; saves h at t == len[row].
// Thread tid owns gate lanes {tid, tid+256, tid+512} of all R rows.
template <int R, int T>
__global__ __launch_bounds__(256) void gru_scan(
    const int* __restrict__ idx,      // [Nrows, T]
    const float* __restrict__ emb,    // [V, 256]
    const float* __restrict__ WihT,   // [256][768] (k-major)
    const float* __restrict__ WhhT,   // [256][768]
    const float* __restrict__ bih,    // [768]
    const float* __restrict__ bhh,    // [768]
    const int* __restrict__ len_idx,  // [Nrows]
    const float* __restrict__ mask,   // [Nrows, T]
    float* __restrict__ out_state)    // [Nrows, 256]
{
    __shared__ float x_lds[R][256];
    __shared__ float h_lds[R][256];
    const int tid  = threadIdx.x;
    const int row0 = blockIdx.x * R;

    for (int r = 0; r < R; ++r) h_lds[r][tid] = 0.f;

    const float bi0 = bih[tid], bi1 = bih[tid + 256], bi2 = bih[tid + 512];
    const float bh0 = bhh[tid], bh1 = bhh[tid + 256], bh2 = bhh[tid + 512];

    int len[R];
#pragma unroll
    for (int r = 0; r < R; ++r) len[r] = len_idx[row0 + r];

    for (int t = 0; t < T; ++t) {
        // stage x rows (embedding gather), coalesced
        for (int r = 0; r < R; ++r) {
            int tok = idx[(row0 + r) * T + t];
            x_lds[r][tid] = emb[(size_t)tok * 256 + tid];
        }
        __syncthreads();  // x ready; also guarantees prev-step h writes visible

        float g0[R], g1[R], g2[R], a0[R], a1[R], a2[R];
#pragma unroll
        for (int r = 0; r < R; ++r) { g0[r]=0.f; g1[r]=0.f; g2[r]=0.f; a0[r]=0.f; a1[r]=0.f; a2[r]=0.f; }

        for (int k2 = 0; k2 < 128; ++k2) {
            const float* wi = WihT + k2 * 2 * G3 + tid;
            const float* wh = WhhT + k2 * 2 * G3 + tid;
            float wia0 = wi[0],   wia1 = wi[256],     wia2 = wi[512];
            float wib0 = wi[768], wib1 = wi[768+256], wib2 = wi[768+512];
            float wha0 = wh[0],   wha1 = wh[256],     wha2 = wh[512];
            float whb0 = wh[768], whb1 = wh[768+256], whb2 = wh[768+512];
#pragma unroll
            for (int r = 0; r < R; ++r) {
                float2 xv = ((const float2*)x_lds[r])[k2];  // broadcast reads
                float2 hv = ((const float2*)h_lds[r])[k2];
                g0[r] = fmaf(wib0, xv.y, fmaf(wia0, xv.x, g0[r]));
                g1[r] = fmaf(wib1, xv.y, fmaf(wia1, xv.x, g1[r]));
                g2[r] = fmaf(wib2, xv.y, fmaf(wia2, xv.x, g2[r]));
                a0[r] = fmaf(whb0, hv.y, fmaf(wha0, hv.x, a0[r]));
                a1[r] = fmaf(whb1, hv.y, fmaf(wha1, hv.x, a1[r]));
                a2[r] = fmaf(whb2, hv.y, fmaf(wha2, hv.x, a2[r]));
            }
        }
        __syncthreads();  // done reading h/x for this step

#pragma unroll
        for (int r = 0; r < R; ++r) {
            float rg = sigmoidf_(g0[r] + bi0 + a0[r] + bh0);
            float zg = sigmoidf_(g1[r] + bi1 + a1[r] + bh1);
            float ng = tanhf(g2[r] + bi2 + rg * (a2[r] + bh2));
            float hnew = (1.f - zg) * ng + zg * h_lds[r][tid];
            h_lds[r][tid] = hnew;  // column-private, safe without extra sync
            if (t == len[r])
                out_state[(size_t)(row0 + r) * 256 + tid] = hnew * mask[(row0 + r) * T + t];
        }
    }
}

// Per-batch attention + fc; also writes target (as float) into d_out tail.
__global__ __launch_bounds__(256) void attn_fc(
    const float* __restrict__ seq_cate,   // [2560][256]
    const float* __restrict__ out_short,  // [256][256]
    const float* __restrict__ mask_seq,   // [256][10]
    const float* __restrict__ fcWT,       // [512][256]
    const float* __restrict__ fc_b,       // [256]
    const int* __restrict__ target,       // [256]
    float* __restrict__ fc_out,           // [256][256]
    float* __restrict__ d_out)            // logits base; target at +25600000
{
    __shared__ float sc[SUBS][256];
    __shared__ float os[256];
    __shared__ float part[SUBS][256];
    __shared__ float mix[512];
    const int b = blockIdx.x, tid = threadIdx.x;

    os[tid] = out_short[b * 256 + tid];
    for (int s = 0; s < SUBS; ++s) sc[s][tid] = seq_cate[(size_t)(b * SUBS + s) * 256 + tid];
    __syncthreads();

    for (int s = 0; s < SUBS; ++s) part[s][tid] = sc[s][tid] * os[tid];
    __syncthreads();
    for (int off = 128; off >= 1; off >>= 1) {
        if (tid < off)
            for (int s = 0; s < SUBS; ++s) part[s][tid] += part[s][tid + off];
        __syncthreads();
    }

    // softmax + mask + renorm (redundant across threads)
    float w[SUBS];
    float m = -1e30f;
    for (int s = 0; s < SUBS; ++s) m = fmaxf(m, part[s][0]);
    float sum = 0.f;
    for (int s = 0; s < SUBS; ++s) { w[s] = expf(part[s][0] - m); sum += w[s]; }
    float tot = 0.f;
    for (int s = 0; s < SUBS; ++s) { w[s] = (w[s] / sum) * mask_seq[b * SUBS + s]; tot += w[s]; }
    float inv = 1.f / tot;

    float sumc = 0.f;
    for (int s = 0; s < SUBS; ++s) sumc += w[s] * inv * sc[s][tid];
    mix[tid] = sumc;
    mix[256 + tid] = os[tid];
    __syncthreads();

    float acc = fc_b[tid];
    for (int j = 0; j < 512; ++j) acc = fmaf(mix[j], fcWT[j * 256 + tid], acc);
    fc_out[b * 256 + tid] = acc;

    if (tid == 0) d_out[(size_t)BATCH * EMB_V + b] = (float)target[b];
}

// logits[b][v] = dot(fc_out[b], emb[v]); M=256 (whole), N tile 64, K tile 32
__global__ __launch_bounds__(256) void logits_gemm(
    const float* __restrict__ A,    // fc_out [256][256]
    const float* __restrict__ emb,  // [V][256]
    float* __restrict__ out)        // [256][V]
{
    __shared__ float As[32][260];  // [k][b], padded for 16B-aligned float4 reads
    __shared__ float Bs[32][68];   // [k][j]
    const int tid = threadIdx.x;
    const int v0  = blockIdx.x * 64;
    const int tx  = tid & 15, ty = tid >> 4;

    float acc[16][4];
#pragma unroll
    for (int i = 0; i < 16; ++i)
#pragma unroll
        for (int j = 0; j < 4; ++j) acc[i][j] = 0.f;

    for (int k0 = 0; k0 < 256; k0 += 32) {
#pragma unroll
        for (int it = 0; it < 32; ++it) {
            int e = tid + it * 256;
            int b_ = e >> 5, k = e & 31;
            As[k][b_] = A[b_ * 256 + k0 + k];
        }
#pragma unroll
        for (int it = 0; it < 8; ++it) {
            int e = tid + it * 256;
            int j = e >> 5, k = e & 31;
            int v = v0 + j;
            Bs[k][j] = (v < EMB_V) ? emb[(size_t)v * 256 + k0 + k] : 0.f;
        }
        __syncthreads();
#pragma unroll
        for (int k = 0; k < 32; ++k) {
            float4 b4 = *(const float4*)&Bs[k][tx * 4];
            float bb[4] = {b4.x, b4.y, b4.z, b4.w};
            float a[16];
#pragma unroll
            for (int i = 0; i < 16; i += 4) {
                float4 a4 = *(const float4*)&As[k][ty * 16 + i];
                a[i] = a4.x; a[i+1] = a4.y; a[i+2] = a4.z; a[i+3] = a4.w;
            }
#pragma unroll
            for (int i = 0; i < 16; ++i)
#pragma unroll
                for (int j = 0; j < 4; ++j) acc[i][j] = fmaf(a[i], bb[j], acc[i][j]);
        }
        __syncthreads();
    }

    const bool full = (v0 + 64 <= EMB_V);
#pragma unroll
    for (int i = 0; i < 16; ++i) {
        int b_ = ty * 16 + i;
        size_t base = (size_t)b_ * EMB_V + v0 + tx * 4;
        if (full) {
            float4 o4 = make_float4(acc[i][0], acc[i][1], acc[i][2], acc[i][3]);
            *(float4*)&out[base] = o4;
        } else {
            for (int j = 0; j < 4; ++j)
                if (v0 + tx * 4 + j < EMB_V) out[base + j] = acc[i][j];
        }
    }
}

extern "C" void kernel_launch(void* const* d_in, const int* in_sizes, int n_in,
                              void* d_out, int out_size, void* d_ws, size_t ws_size,
                              hipStream_t stream) {
    const int*   input_cate   = (const int*)d_in[0];
    const float* mask_cate    = (const float*)d_in[1];
    const float* mask_seq     = (const float*)d_in[2];
    const int*   subseqLen    = (const int*)d_in[5];
    const int*   input_batch  = (const int*)d_in[7];
    const float* mask_batch   = (const float*)d_in[8];
    const int*   seqLen_batch = (const int*)d_in[9];
    const int*   target       = (const int*)d_in[10];
    const float* emb          = (const float*)d_in[12];
    const float* Wih_c        = (const float*)d_in[13];
    const float* Whh_c        = (const float*)d_in[14];
    const float* bih_c        = (const float*)d_in[15];
    const float* bhh_c        = (const float*)d_in[16];
    const float* Wih_s        = (const float*)d_in[17];
    const float* Whh_s        = (const float*)d_in[18];
    const float* bih_s        = (const float*)d_in[19];
    const float* bhh_s        = (const float*)d_in[20];
    const float* fc_W         = (const float*)d_in[21];
    const float* fc_b         = (const float*)d_in[22];
    float* out = (float*)d_out;

    float* ws = (float*)d_ws;
    float* WihT_c   = ws;                 // 196608
    float* WhhT_c   = ws + 196608;        // 196608
    float* WihT_s   = ws + 393216;        // 196608
    float* WhhT_s   = ws + 589824;        // 196608
    float* fcWT     = ws + 786432;        // 131072
    float* seq_cate = ws + 917504;        // 655360
    float* out_short= ws + 1572864;       // 65536
    float* fc_out   = ws + 1638400;       // 65536

    transpose_rm<<<768, 256, 0, stream>>>(Wih_c, WihT_c, G3, 256);
    transpose_rm<<<768, 256, 0, stream>>>(Whh_c, WhhT_c, G3, 256);
    transpose_rm<<<768, 256, 0, stream>>>(Wih_s, WihT_s, G3, 256);
    transpose_rm<<<768, 256, 0, stream>>>(Whh_s, WhhT_s, G3, 256);
    transpose_rm<<<512, 256, 0, stream>>>(fc_W, fcWT, 256, 512);

    gru_scan<8, TC><<<BC / 8, 256, 0, stream>>>(
        input_cate, emb, WihT_c, WhhT_c, bih_c, bhh_c, subseqLen, mask_cate, seq_cate);
    gru_scan<2, TS><<<BATCH / 2, 256, 0, stream>>>(
        input_batch, emb, WihT_s, WhhT_s, bih_s, bhh_s, seqLen_batch, mask_batch, out_short);

    attn_fc<<<BATCH, 256, 0, stream>>>(
        seq_cate, out_short, mask_seq, fcWT, fc_b, target, fc_out, out);

    logits_gemm<<<(EMB_V + 63) / 64, 256, 0, stream>>>(fc_out, emb, out);
}

// Round 2
// 1682.254 us; speedup vs baseline: 1.8908x; 1.8908x over previous
//
#include <hip/hip_runtime.h>
#include <cmath>

#define EMB_V 100000
#define BATCH 256
#define SUBS  10
#define BC    2560
#define TC    20
#define TS    50

using bf16x8 = __attribute__((ext_vector_type(8))) short;
using f32x4  = __attribute__((ext_vector_type(4))) float;

__device__ __forceinline__ float sigmoidf_(float x) { return 1.f / (1.f + __expf(-x)); }

__device__ __forceinline__ unsigned short f2bf(float f) {
    unsigned int u = __float_as_uint(f);
    u += 0x7fff + ((u >> 16) & 1);   // RNE
    return (unsigned short)(u >> 16);
}
__device__ __forceinline__ float bf2f(unsigned short u) {
    return __uint_as_float(((unsigned int)u) << 16);
}

// out[c*rows + r] = in[r*cols + c]  (for fc_W -> fcWT)
__global__ void transpose_rm(const float* __restrict__ in, float* __restrict__ out,
                             int rows, int cols) {
    int o = blockIdx.x * 256 + threadIdx.x;
    if (o >= rows * cols) return;
    int c = o / rows;
    int r = o - c * rows;
    out[o] = in[r * cols + c];
}

// Pack Whh [768][256] fp32 into MFMA B-fragment-contiguous bf16 layout:
// frag fi = nt*8+kc (nt<48, kc<8); lane l holds B[k][n] = Whh[n][k],
// n = nt*16+(l&15), k = kc*32+(l>>4)*8+j, j=0..7. dst[fi*64 + l][8 bf16].
__global__ void pack_whh(const float* __restrict__ W, unsigned short* __restrict__ P) {
    int t = blockIdx.x * 256 + threadIdx.x;
    if (t >= 48 * 8 * 64) return;
    int l = t & 63, kc = (t >> 6) & 7, nt = t >> 9;
    int n = nt * 16 + (l & 15);
    int k = kc * 32 + (l >> 4) * 8;
    const float* src = W + n * 256 + k;
    unsigned short* dst = P + (size_t)t * 8;
#pragma unroll
    for (int j = 0; j < 8; ++j) dst[j] = f2bf(src[j]);
}

// Generic C[m][n] = sum_k A[m][k]*B[n][k], K=256 fixed, BM=BN=128.
// GATHER: A row m comes from A[tok[m]] (embedding gather).
// OBF16: output stored bf16; else fp32. NGUARD: guard n < N.
template <bool GATHER, bool OBF16, bool NGUARD>
__global__ __launch_bounds__(256, 2) void gemm_abt(
    const float* __restrict__ A, const int* __restrict__ tok,
    const float* __restrict__ B, void* __restrict__ Cout,
    int N, int ldc)
{
    __shared__ unsigned short Asub[128][72];
    __shared__ unsigned short Bsub[128][72];
    const int tid = threadIdx.x;
    const int l = tid & 63, wave = tid >> 6;
    const int lm = l & 15, quad = l >> 4;
    const int wm = wave >> 1, wn = wave & 1;
    const int n0 = blockIdx.x * 128, m0 = blockIdx.y * 128;

    f32x4 acc[4][4];
#pragma unroll
    for (int mi = 0; mi < 4; ++mi)
#pragma unroll
        for (int ni = 0; ni < 4; ++ni) acc[mi][ni] = (f32x4){0.f, 0.f, 0.f, 0.f};

    for (int kk = 0; kk < 4; ++kk) {
        const int k0 = kk * 64;
#pragma unroll
        for (int i = 0; i < 8; ++i) {
            int slot = tid + i * 256;
            int row = slot >> 4, c4 = (slot & 15) * 4;
            const float* src = GATHER
                ? A + (size_t)tok[m0 + row] * 256 + k0 + c4
                : A + (size_t)(m0 + row) * 256 + k0 + c4;
            float4 v = *(const float4*)src;
            *(ushort4*)&Asub[row][c4] = make_ushort4(f2bf(v.x), f2bf(v.y), f2bf(v.z), f2bf(v.w));
        }
#pragma unroll
        for (int i = 0; i < 8; ++i) {
            int slot = tid + i * 256;
            int row = slot >> 4, c4 = (slot & 15) * 4;
            int n = n0 + row;
            float4 v;
            if (!NGUARD || n < N) v = *(const float4*)(B + (size_t)n * 256 + k0 + c4);
            else                  v = make_float4(0.f, 0.f, 0.f, 0.f);
            *(ushort4*)&Bsub[row][c4] = make_ushort4(f2bf(v.x), f2bf(v.y), f2bf(v.z), f2bf(v.w));
        }
        __syncthreads();
#pragma unroll
        for (int kc = 0; kc < 2; ++kc) {
            bf16x8 af[4], bfv[4];
#pragma unroll
            for (int mi = 0; mi < 4; ++mi)
                af[mi] = *(const bf16x8*)&Asub[wm * 64 + mi * 16 + lm][kc * 32 + quad * 8];
#pragma unroll
            for (int ni = 0; ni < 4; ++ni)
                bfv[ni] = *(const bf16x8*)&Bsub[wn * 64 + ni * 16 + lm][kc * 32 + quad * 8];
#pragma unroll
            for (int mi = 0; mi < 4; ++mi)
#pragma unroll
                for (int ni = 0; ni < 4; ++ni)
                    acc[mi][ni] = __builtin_amdgcn_mfma_f32_16x16x32_bf16(
                        af[mi], bfv[ni], acc[mi][ni], 0, 0, 0);
        }
        __syncthreads();
    }
    // epilogue: C/D layout col=lane&15, row=quad*4+reg
#pragma unroll
    for (int mi = 0; mi < 4; ++mi)
#pragma unroll
        for (int ni = 0; ni < 4; ++ni) {
            int col = n0 + wn * 64 + ni * 16 + lm;
            if (NGUARD && col >= N) continue;
#pragma unroll
            for (int i = 0; i < 4; ++i) {
                int row = m0 + wm * 64 + mi * 16 + quad * 4 + i;
                if (OBF16)
                    ((unsigned short*)Cout)[(size_t)row * ldc + col] = f2bf(acc[mi][ni][i]);
                else
                    ((float*)Cout)[(size_t)row * ldc + col] = acc[mi][ni][i];
            }
        }
}

// MFMA GRU scan: block owns 16 rows; per step gh = h @ WhhT via MFMA,
// gi precomputed (bf16). h kept bf16 in LDS. 4 waves x 192 N-cols each.
template <int T>
__global__ __launch_bounds__(256, 2) void gru_scan_mfma(
    const unsigned short* __restrict__ gi,      // [Nrows*T][768] bf16
    const unsigned short* __restrict__ packedW, // 48*8 frags * 64 lanes * 8 bf16
    const float* __restrict__ bih, const float* __restrict__ bhh,
    const int* __restrict__ len_idx, const float* __restrict__ mask,
    float* __restrict__ out_state)
{
    __shared__ unsigned short h_lds[16][264];   // +8 pad: 2-way-conflict-free b128 reads
    __shared__ float gh_lds[16][772];
    const int tid = threadIdx.x;
    const int l = tid & 63, wave = tid >> 6;
    const int lm = l & 15, quad = l >> 4;
    const int row0 = blockIdx.x * 16;

    for (int i = tid; i < 16 * 264; i += 256) ((unsigned short*)h_lds)[i] = 0;

    const float bi0 = bih[tid], bi1 = bih[tid + 256], bi2 = bih[tid + 512];
    const float bh0 = bhh[tid], bh1 = bhh[tid + 256], bh2 = bhh[tid + 512];
    int len[16];
#pragma unroll
    for (int r = 0; r < 16; ++r) len[r] = len_idx[row0 + r];
    __syncthreads();

    for (int t = 0; t < T; ++t) {
        // prefetch this step's gi into registers (independent of h / MFMA)
        unsigned short g0p[16], g1p[16], g2p[16];
#pragma unroll
        for (int r = 0; r < 16; ++r) {
            const unsigned short* gp = gi + ((size_t)(row0 + r) * T + t) * 768 + tid;
            g0p[r] = gp[0]; g1p[r] = gp[256]; g2p[r] = gp[512];
        }

        // gh = h @ WhhT
        f32x4 acc[12];
#pragma unroll
        for (int nt = 0; nt < 12; ++nt) acc[nt] = (f32x4){0.f, 0.f, 0.f, 0.f};
        bf16x8 a[8];
#pragma unroll
        for (int kc = 0; kc < 8; ++kc)
            a[kc] = *(const bf16x8*)&h_lds[lm][kc * 32 + quad * 8];
#pragma unroll
        for (int nt = 0; nt < 12; ++nt) {
            const int ntg = wave * 12 + nt;
            const bf16x8* bp = (const bf16x8*)packedW + (size_t)ntg * 512 + l;
#pragma unroll
            for (int kc = 0; kc < 8; ++kc) {
                bf16x8 b = bp[kc * 64];
                acc[nt] = __builtin_amdgcn_mfma_f32_16x16x32_bf16(a[kc], b, acc[nt], 0, 0, 0);
            }
        }
#pragma unroll
        for (int nt = 0; nt < 12; ++nt) {
            const int col = wave * 192 + nt * 16 + lm;
#pragma unroll
            for (int i = 0; i < 4; ++i)
                gh_lds[quad * 4 + i][col] = acc[nt][i];
        }
        __syncthreads();

        // gates: thread tid = hidden unit j
        const int j = tid;
#pragma unroll 4
        for (int r = 0; r < 16; ++r) {
            float rg = sigmoidf_(bf2f(g0p[r]) + bi0 + gh_lds[r][j] + bh0);
            float zg = sigmoidf_(bf2f(g1p[r]) + bi1 + gh_lds[r][j + 256] + bh1);
            float ng = tanhf(bf2f(g2p[r]) + bi2 + rg * (gh_lds[r][j + 512] + bh2));
            float hold = bf2f(h_lds[r][j]);
            float hnew = (1.f - zg) * ng + zg * hold;
            h_lds[r][j] = f2bf(hnew);
            if (t == len[r])
                out_state[(size_t)(row0 + r) * 256 + j] = hnew * mask[(row0 + r) * T + t];
        }
        __syncthreads();
    }
}

// Per-batch attention + fc; also writes target (as float) into d_out tail.
__global__ __launch_bounds__(256) void attn_fc(
    const float* __restrict__ seq_cate, const float* __restrict__ out_short,
    const float* __restrict__ mask_seq, const float* __restrict__ fcWT,
    const float* __restrict__ fc_b, const int* __restrict__ target,
    float* __restrict__ fc_out, float* __restrict__ d_out)
{
    __shared__ float sc[SUBS][256];
    __shared__ float os[256];
    __shared__ float part[SUBS][256];
    __shared__ float mix[512];
    const int b = blockIdx.x, tid = threadIdx.x;

    os[tid] = out_short[b * 256 + tid];
    for (int s = 0; s < SUBS; ++s) sc[s][tid] = seq_cate[(size_t)(b * SUBS + s) * 256 + tid];
    __syncthreads();

    for (int s = 0; s < SUBS; ++s) part[s][tid] = sc[s][tid] * os[tid];
    __syncthreads();
    for (int off = 128; off >= 1; off >>= 1) {
        if (tid < off)
            for (int s = 0; s < SUBS; ++s) part[s][tid] += part[s][tid + off];
        __syncthreads();
    }

    float w[SUBS];
    float m = -1e30f;
    for (int s = 0; s < SUBS; ++s) m = fmaxf(m, part[s][0]);
    float sum = 0.f;
    for (int s = 0; s < SUBS; ++s) { w[s] = __expf(part[s][0] - m); sum += w[s]; }
    float tot = 0.f;
    for (int s = 0; s < SUBS; ++s) { w[s] = (w[s] / sum) * mask_seq[b * SUBS + s]; tot += w[s]; }
    float inv = 1.f / tot;

    float sumc = 0.f;
    for (int s = 0; s < SUBS; ++s) sumc += w[s] * inv * sc[s][tid];
    mix[tid] = sumc;
    mix[256 + tid] = os[tid];
    __syncthreads();

    float acc = fc_b[tid];
    for (int jj = 0; jj < 512; ++jj) acc = fmaf(mix[jj], fcWT[jj * 256 + tid], acc);
    fc_out[b * 256 + tid] = acc;

    if (tid == 0) d_out[(size_t)BATCH * EMB_V + b] = (float)target[b];
}

extern "C" void kernel_launch(void* const* d_in, const int* in_sizes, int n_in,
                              void* d_out, int out_size, void* d_ws, size_t ws_size,
                              hipStream_t stream) {
    const int*   input_cate   = (const int*)d_in[0];
    const float* mask_cate    = (const float*)d_in[1];
    const float* mask_seq     = (const float*)d_in[2];
    const int*   subseqLen    = (const int*)d_in[5];
    const int*   input_batch  = (const int*)d_in[7];
    const float* mask_batch   = (const float*)d_in[8];
    const int*   seqLen_batch = (const int*)d_in[9];
    const int*   target       = (const int*)d_in[10];
    const float* emb          = (const float*)d_in[12];
    const float* Wih_c        = (const float*)d_in[13];
    const float* Whh_c        = (const float*)d_in[14];
    const float* bih_c        = (const float*)d_in[15];
    const float* bhh_c        = (const float*)d_in[16];
    const float* Wih_s        = (const float*)d_in[17];
    const float* Whh_s        = (const float*)d_in[18];
    const float* bih_s        = (const float*)d_in[19];
    const float* bhh_s        = (const float*)d_in[20];
    const float* fc_W         = (const float*)d_in[21];
    const float* fc_b         = (const float*)d_in[22];
    float* out = (float*)d_out;

    float* ws = (float*)d_ws;
    float* fcWT       = ws;                      // 131072 f
    float* out_short  = ws + 131072;             // 65536
    float* fc_out     = ws + 196608;             // 65536
    float* seq_cate   = ws + 262144;             // 655360
    unsigned short* packW_c = (unsigned short*)(ws + 917504);   // 196608 us = 98304 f
    unsigned short* packW_s = (unsigned short*)(ws + 1015808);  // 98304 f
    unsigned short* gi_c    = (unsigned short*)(ws + 1114112);  // 39321600 us = 19660800 f
    unsigned short* gi_s    = (unsigned short*)(ws + 20774912); // 9830400 us = 4915200 f
    // total ws use: 25690112 floats ~= 103 MB

    transpose_rm<<<512, 256, 0, stream>>>(fc_W, fcWT, 256, 512);
    pack_whh<<<96, 256, 0, stream>>>(Whh_c, packW_c);
    pack_whh<<<96, 256, 0, stream>>>(Whh_s, packW_s);

    // input-gate GEMMs: gi = emb[tok] @ Wih^T  (bf16 out)
    gemm_abt<true, true, false><<<dim3(6, 400), 256, 0, stream>>>(
        emb, input_cate, Wih_c, gi_c, 768, 768);
    gemm_abt<true, true, false><<<dim3(6, 100), 256, 0, stream>>>(
        emb, input_batch, Wih_s, gi_s, 768, 768);

    // recurrent scans
    gru_scan_mfma<TC><<<BC / 16, 256, 0, stream>>>(
        gi_c, packW_c, bih_c, bhh_c, subseqLen, mask_cate, seq_cate);
    gru_scan_mfma<TS><<<BATCH / 16, 256, 0, stream>>>(
        gi_s, packW_s, bih_s, bhh_s, seqLen_batch, mask_batch, out_short);

    attn_fc<<<BATCH, 256, 0, stream>>>(
        seq_cate, out_short, mask_seq, fcWT, fc_b, target, fc_out, out);

    // logits = fc_out @ emb^T  (fp32 out)
    gemm_abt<false, false, true><<<dim3(782, 2), 256, 0, stream>>>(
        fc_out, nullptr, emb, out, EMB_V, EMB_V);
}

// Round 3
// 734.370 us; speedup vs baseline: 4.3313x; 2.2907x over previous
//
#include <hip/hip_runtime.h>
#include <cmath>

#define EMB_V 100000
#define BATCH 256
#define SUBS  10
#define BC    2560
#define TC    20
#define TS    50

using bf16x8 = __attribute__((ext_vector_type(8))) short;
using f32x4  = __attribute__((ext_vector_type(4))) float;

__device__ __forceinline__ float sigmoidf_(float x) { return 1.f / (1.f + __expf(-x)); }

__device__ __forceinline__ unsigned short f2bf(float f) {
    unsigned int u = __float_as_uint(f);
    u += 0x7fff + ((u >> 16) & 1);   // RNE
    return (unsigned short)(u >> 16);
}
__device__ __forceinline__ float bf2f(unsigned short u) {
    return __uint_as_float(((unsigned int)u) << 16);
}

// out[c*rows + r] = in[r*cols + c]  (for fc_W -> fcWT)
__global__ void transpose_rm(const float* __restrict__ in, float* __restrict__ out,
                             int rows, int cols) {
    int o = blockIdx.x * 256 + threadIdx.x;
    if (o >= rows * cols) return;
    int c = o / rows;
    int r = o - c * rows;
    out[o] = in[r * cols + c];
}

// Pack Whh [768][256] fp32 into MFMA B-fragment-contiguous bf16 layout:
// frag fi = nt*8+kc (nt<48, kc<8); lane l holds B[k][n] = Whh[n][k],
// n = nt*16+(l&15), k = kc*32+(l>>4)*8+j, j=0..7. dst[fi*64 + l][8 bf16].
__global__ void pack_whh(const float* __restrict__ W, unsigned short* __restrict__ P) {
    int t = blockIdx.x * 256 + threadIdx.x;
    if (t >= 48 * 8 * 64) return;
    int l = t & 63, kc = (t >> 6) & 7, nt = t >> 9;
    int n = nt * 16 + (l & 15);
    int k = kc * 32 + (l >> 4) * 8;
    const float* src = W + n * 256 + k;
    unsigned short* dst = P + (size_t)t * 8;
#pragma unroll
    for (int j = 0; j < 8; ++j) dst[j] = f2bf(src[j]);
}

// Generic C[m][n] = sum_k A[m][k]*B[n][k], K=256 fixed, BM=BN=128.
template <bool GATHER, bool OBF16, bool NGUARD>
__global__ __launch_bounds__(256, 2) void gemm_abt(
    const float* __restrict__ A, const int* __restrict__ tok,
    const float* __restrict__ B, void* __restrict__ Cout,
    int N, int ldc)
{
    __shared__ unsigned short Asub[128][72];
    __shared__ unsigned short Bsub[128][72];
    const int tid = threadIdx.x;
    const int l = tid & 63, wave = tid >> 6;
    const int lm = l & 15, quad = l >> 4;
    const int wm = wave >> 1, wn = wave & 1;
    const int n0 = blockIdx.x * 128, m0 = blockIdx.y * 128;

    f32x4 acc[4][4];
#pragma unroll
    for (int mi = 0; mi < 4; ++mi)
#pragma unroll
        for (int ni = 0; ni < 4; ++ni) acc[mi][ni] = (f32x4){0.f, 0.f, 0.f, 0.f};

    for (int kk = 0; kk < 4; ++kk) {
        const int k0 = kk * 64;
#pragma unroll
        for (int i = 0; i < 8; ++i) {
            int slot = tid + i * 256;
            int row = slot >> 4, c4 = (slot & 15) * 4;
            const float* src = GATHER
                ? A + (size_t)tok[m0 + row] * 256 + k0 + c4
                : A + (size_t)(m0 + row) * 256 + k0 + c4;
            float4 v = *(const float4*)src;
            *(ushort4*)&Asub[row][c4] = make_ushort4(f2bf(v.x), f2bf(v.y), f2bf(v.z), f2bf(v.w));
        }
#pragma unroll
        for (int i = 0; i < 8; ++i) {
            int slot = tid + i * 256;
            int row = slot >> 4, c4 = (slot & 15) * 4;
            int n = n0 + row;
            float4 v;
            if (!NGUARD || n < N) v = *(const float4*)(B + (size_t)n * 256 + k0 + c4);
            else                  v = make_float4(0.f, 0.f, 0.f, 0.f);
            *(ushort4*)&Bsub[row][c4] = make_ushort4(f2bf(v.x), f2bf(v.y), f2bf(v.z), f2bf(v.w));
        }
        __syncthreads();
#pragma unroll
        for (int kc = 0; kc < 2; ++kc) {
            bf16x8 af[4], bfv[4];
#pragma unroll
            for (int mi = 0; mi < 4; ++mi)
                af[mi] = *(const bf16x8*)&Asub[wm * 64 + mi * 16 + lm][kc * 32 + quad * 8];
#pragma unroll
            for (int ni = 0; ni < 4; ++ni)
                bfv[ni] = *(const bf16x8*)&Bsub[wn * 64 + ni * 16 + lm][kc * 32 + quad * 8];
#pragma unroll
            for (int mi = 0; mi < 4; ++mi)
#pragma unroll
                for (int ni = 0; ni < 4; ++ni)
                    acc[mi][ni] = __builtin_amdgcn_mfma_f32_16x16x32_bf16(
                        af[mi], bfv[ni], acc[mi][ni], 0, 0, 0);
        }
        __syncthreads();
    }
#pragma unroll
    for (int mi = 0; mi < 4; ++mi)
#pragma unroll
        for (int ni = 0; ni < 4; ++ni) {
            int col = n0 + wn * 64 + ni * 16 + lm;
            if (NGUARD && col >= N) continue;
#pragma unroll
            for (int i = 0; i < 4; ++i) {
                int row = m0 + wm * 64 + mi * 16 + quad * 4 + i;
                if (OBF16)
                    ((unsigned short*)Cout)[(size_t)row * ldc + col] = f2bf(acc[mi][ni][i]);
                else
                    ((float*)Cout)[(size_t)row * ldc + col] = acc[mi][ni][i];
            }
        }
}

// Fused GRU scans (cat: blocks 0..159, T=20; short: blocks 160..175, T=50).
// 1024 threads = 16 waves; each wave computes 3 N-tiles of gh = h @ WhhT.
// 16 rows/block; h bf16 in LDS; gi precomputed bf16 (register-prefetched).
__global__ __launch_bounds__(1024, 4) void gru_scan_fused(
    const unsigned short* __restrict__ gi_c, const unsigned short* __restrict__ pW_c,
    const float* __restrict__ bih_c, const float* __restrict__ bhh_c,
    const int* __restrict__ len_c, const float* __restrict__ mask_c,
    float* __restrict__ out_c,
    const unsigned short* __restrict__ gi_s, const unsigned short* __restrict__ pW_s,
    const float* __restrict__ bih_s, const float* __restrict__ bhh_s,
    const int* __restrict__ len_s, const float* __restrict__ mask_s,
    float* __restrict__ out_s)
{
    __shared__ unsigned short h_lds[16][264];
    __shared__ float gh_lds[16][772];

    const bool is_cat = blockIdx.x < (BC / 16);
    const int  T      = is_cat ? TC : TS;
    const int  row0   = (is_cat ? blockIdx.x : blockIdx.x - BC / 16) * 16;
    const unsigned short* gi   = is_cat ? gi_c  : gi_s;
    const unsigned short* pW   = is_cat ? pW_c  : pW_s;
    const float*          bih  = is_cat ? bih_c : bih_s;
    const float*          bhh  = is_cat ? bhh_c : bhh_s;
    const int*            lenp = is_cat ? len_c : len_s;
    const float*          mask = is_cat ? mask_c : mask_s;
    float*                outp = is_cat ? out_c : out_s;

    const int tid  = threadIdx.x;
    const int l    = tid & 63, wave = tid >> 6;
    const int lm   = l & 15,   quad = l >> 4;
    const int j    = tid & 255;
    const int rbase = (tid >> 8) * 4;

    for (int i = tid; i < 16 * 264; i += 1024) ((unsigned short*)h_lds)[i] = 0;

    const float bi0 = bih[j], bi1 = bih[j + 256], bi2 = bih[j + 512];
    const float bh0 = bhh[j], bh1 = bhh[j + 256], bh2 = bhh[j + 512];
    int len[4];
#pragma unroll
    for (int k = 0; k < 4; ++k) len[k] = lenp[row0 + rbase + k];
    __syncthreads();

    for (int t = 0; t < T; ++t) {
        // prefetch this step's gi into registers (overlaps MFMA phase)
        unsigned short gp[4][3];
#pragma unroll
        for (int k = 0; k < 4; ++k) {
            const unsigned short* g = gi + ((size_t)(row0 + rbase + k) * T + t) * 768 + j;
            gp[k][0] = g[0]; gp[k][1] = g[256]; gp[k][2] = g[512];
        }

        // gh = h @ WhhT : wave handles N-tiles ntg = wave*3 .. wave*3+2
        bf16x8 a[8];
#pragma unroll
        for (int kc = 0; kc < 8; ++kc)
            a[kc] = *(const bf16x8*)&h_lds[lm][kc * 32 + quad * 8];

        f32x4 acc[3];
#pragma unroll
        for (int nt = 0; nt < 3; ++nt) acc[nt] = (f32x4){0.f, 0.f, 0.f, 0.f};
#pragma unroll
        for (int nt = 0; nt < 3; ++nt) {
            const int ntg = wave * 3 + nt;
            const bf16x8* bp = (const bf16x8*)pW + (size_t)ntg * 512 + l;
#pragma unroll
            for (int kc = 0; kc < 8; ++kc) {
                bf16x8 b = bp[kc * 64];
                acc[nt] = __builtin_amdgcn_mfma_f32_16x16x32_bf16(a[kc], b, acc[nt], 0, 0, 0);
            }
        }
#pragma unroll
        for (int nt = 0; nt < 3; ++nt) {
            const int col = (wave * 3 + nt) * 16 + lm;
#pragma unroll
            for (int i = 0; i < 4; ++i)
                gh_lds[quad * 4 + i][col] = acc[nt][i];
        }
        __syncthreads();

        // gates: thread owns (r = rbase+k, j) for k=0..3
#pragma unroll
        for (int k = 0; k < 4; ++k) {
            const int r = rbase + k;
            float rg = sigmoidf_(bf2f(gp[k][0]) + bi0 + gh_lds[r][j] + bh0);
            float zg = sigmoidf_(bf2f(gp[k][1]) + bi1 + gh_lds[r][j + 256] + bh1);
            float ng = tanhf(bf2f(gp[k][2]) + bi2 + rg * (gh_lds[r][j + 512] + bh2));
            float hold = bf2f(h_lds[r][j]);
            float hnew = (1.f - zg) * ng + zg * hold;
            h_lds[r][j] = f2bf(hnew);
            if (t == len[k])
                outp[(size_t)(row0 + r) * 256 + j] = hnew * mask[(row0 + r) * T + t];
        }
        __syncthreads();
    }
}

// Per-batch attention + fc; also writes target (as float) into d_out tail.
__global__ __launch_bounds__(256) void attn_fc(
    const float* __restrict__ seq_cate, const float* __restrict__ out_short,
    const float* __restrict__ mask_seq, const float* __restrict__ fcWT,
    const float* __restrict__ fc_b, const int* __restrict__ target,
    float* __restrict__ fc_out, float* __restrict__ d_out)
{
    __shared__ float sc[SUBS][256];
    __shared__ float os[256];
    __shared__ float part[SUBS][256];
    __shared__ float mix[512];
    const int b = blockIdx.x, tid = threadIdx.x;

    os[tid] = out_short[b * 256 + tid];
    for (int s = 0; s < SUBS; ++s) sc[s][tid] = seq_cate[(size_t)(b * SUBS + s) * 256 + tid];
    __syncthreads();

    for (int s = 0; s < SUBS; ++s) part[s][tid] = sc[s][tid] * os[tid];
    __syncthreads();
    for (int off = 128; off >= 1; off >>= 1) {
        if (tid < off)
            for (int s = 0; s < SUBS; ++s) part[s][tid] += part[s][tid + off];
        __syncthreads();
    }

    float w[SUBS];
    float m = -1e30f;
    for (int s = 0; s < SUBS; ++s) m = fmaxf(m, part[s][0]);
    float sum = 0.f;
    for (int s = 0; s < SUBS; ++s) { w[s] = __expf(part[s][0] - m); sum += w[s]; }
    float tot = 0.f;
    for (int s = 0; s < SUBS; ++s) { w[s] = (w[s] / sum) * mask_seq[b * SUBS + s]; tot += w[s]; }
    float inv = 1.f / tot;

    float sumc = 0.f;
    for (int s = 0; s < SUBS; ++s) sumc += w[s] * inv * sc[s][tid];
    mix[tid] = sumc;
    mix[256 + tid] = os[tid];
    __syncthreads();

    float acc = fc_b[tid];
    for (int jj = 0; jj < 512; ++jj) acc = fmaf(mix[jj], fcWT[jj * 256 + tid], acc);
    fc_out[b * 256 + tid] = acc;

    if (tid == 0) d_out[(size_t)BATCH * EMB_V + b] = (float)target[b];
}

extern "C" void kernel_launch(void* const* d_in, const int* in_sizes, int n_in,
                              void* d_out, int out_size, void* d_ws, size_t ws_size,
                              hipStream_t stream) {
    const int*   input_cate   = (const int*)d_in[0];
    const float* mask_cate    = (const float*)d_in[1];
    const float* mask_seq     = (const float*)d_in[2];
    const int*   subseqLen    = (const int*)d_in[5];
    const int*   input_batch  = (const int*)d_in[7];
    const float* mask_batch   = (const float*)d_in[8];
    const int*   seqLen_batch = (const int*)d_in[9];
    const int*   target       = (const int*)d_in[10];
    const float* emb          = (const float*)d_in[12];
    const float* Wih_c        = (const float*)d_in[13];
    const float* Whh_c        = (const float*)d_in[14];
    const float* bih_c        = (const float*)d_in[15];
    const float* bhh_c        = (const float*)d_in[16];
    const float* Wih_s        = (const float*)d_in[17];
    const float* Whh_s        = (const float*)d_in[18];
    const float* bih_s        = (const float*)d_in[19];
    const float* bhh_s        = (const float*)d_in[20];
    const float* fc_W         = (const float*)d_in[21];
    const float* fc_b         = (const float*)d_in[22];
    float* out = (float*)d_out;

    float* ws = (float*)d_ws;
    float* fcWT       = ws;                      // 131072 f
    float* out_short  = ws + 131072;             // 65536
    float* fc_out     = ws + 196608;             // 65536
    float* seq_cate   = ws + 262144;             // 655360
    unsigned short* packW_c = (unsigned short*)(ws + 917504);   // 98304 f
    unsigned short* packW_s = (unsigned short*)(ws + 1015808);  // 98304 f
    unsigned short* gi_c    = (unsigned short*)(ws + 1114112);  // 19660800 f
    unsigned short* gi_s    = (unsigned short*)(ws + 20774912); // 4915200 f

    transpose_rm<<<512, 256, 0, stream>>>(fc_W, fcWT, 256, 512);
    pack_whh<<<96, 256, 0, stream>>>(Whh_c, packW_c);
    pack_whh<<<96, 256, 0, stream>>>(Whh_s, packW_s);

    // input-gate GEMMs: gi = emb[tok] @ Wih^T  (bf16 out)
    gemm_abt<true, true, false><<<dim3(6, 400), 256, 0, stream>>>(
        emb, input_cate, Wih_c, gi_c, 768, 768);
    gemm_abt<true, true, false><<<dim3(6, 100), 256, 0, stream>>>(
        emb, input_batch, Wih_s, gi_s, 768, 768);

    // fused recurrent scans: 160 cat blocks + 16 short blocks
    gru_scan_fused<<<BC / 16 + BATCH / 16, 1024, 0, stream>>>(
        gi_c, packW_c, bih_c, bhh_c, subseqLen, mask_cate, seq_cate,
        gi_s, packW_s, bih_s, bhh_s, seqLen_batch, mask_batch, out_short);

    attn_fc<<<BATCH, 256, 0, stream>>>(
        seq_cate, out_short, mask_seq, fcWT, fc_b, target, fc_out, out);

    // logits = fc_out @ emb^T  (fp32 out)
    gemm_abt<false, false, true><<<dim3(782, 2), 256, 0, stream>>>(
        fc_out, nullptr, emb, out, EMB_V, EMB_V);
}